// Round 1
// baseline (2018.636 us; speedup 1.0000x reference)
//
#include <hip/hip_runtime.h>

#define N_NODES 200000
#define N_EDGES 2000000
#define BATCH   1024
#define SEQ     1000
#define EMBD    128
#define VOC     26
#define BN_EPS  1e-5f

// ---------------- graph branch ----------------

// y = x @ W1a  (78->32); also agg = y (self term init)
__global__ __launch_bounds__(128) void k_proj78(const float* __restrict__ x,
                                                const float* __restrict__ W,
                                                float* __restrict__ y,
                                                float* __restrict__ agg) {
    __shared__ __align__(16) float xs[128 * 78];
    __shared__ __align__(16) float ws[78 * 32];
    int tid = threadIdx.x;
    int base = blockIdx.x * 128;
    for (int i = tid; i < 78 * 32; i += 128) ws[i] = W[i];
    int cnt = min(128, N_NODES - base);
    for (int i = tid; i < cnt * 78; i += 128) xs[i] = x[(size_t)base * 78 + i];
    __syncthreads();
    int n = base + tid;
    if (tid >= cnt) return;
    float acc[32];
#pragma unroll
    for (int j = 0; j < 32; j++) acc[j] = 0.f;
    const float* xr = &xs[tid * 78];
    for (int c = 0; c < 78; c++) {
        float xv = xr[c];
        const float4* w4 = (const float4*)&ws[c * 32];
#pragma unroll
        for (int j4 = 0; j4 < 8; j4++) {
            float4 w = w4[j4];
            acc[j4 * 4 + 0] += xv * w.x; acc[j4 * 4 + 1] += xv * w.y;
            acc[j4 * 4 + 2] += xv * w.z; acc[j4 * 4 + 3] += xv * w.w;
        }
    }
    float4* yo = (float4*)&y[(size_t)n * 32];
    float4* ao = (float4*)&agg[(size_t)n * 32];
#pragma unroll
    for (int j4 = 0; j4 < 8; j4++) {
        float4 v = make_float4(acc[j4*4], acc[j4*4+1], acc[j4*4+2], acc[j4*4+3]);
        yo[j4] = v; ao[j4] = v;
    }
}

// y = (h*a + c) @ W (32->32); agg = y
__global__ __launch_bounds__(256) void k_proj32(const float* __restrict__ hbuf,
                                                const float* __restrict__ aff,
                                                const float* __restrict__ W,
                                                float* __restrict__ y,
                                                float* __restrict__ agg) {
    __shared__ __align__(16) float ts[256 * 33];
    __shared__ __align__(16) float ws[1024];
    __shared__ float as_[32], cs_[32];
    int tid = threadIdx.x, base = blockIdx.x * 256;
    for (int i = tid; i < 1024; i += 256) ws[i] = W[i];
    if (tid < 32) { as_[tid] = aff[tid]; cs_[tid] = aff[32 + tid]; }
    int cnt = min(256, N_NODES - base);
    for (int i = tid; i < cnt * 32; i += 256) ts[(i >> 5) * 33 + (i & 31)] = hbuf[(size_t)base * 32 + i];
    __syncthreads();
    if (tid >= cnt) return;
    float acc[32];
#pragma unroll
    for (int j = 0; j < 32; j++) acc[j] = 0.f;
    for (int c = 0; c < 32; c++) {
        float zv = ts[tid * 33 + c] * as_[c] + cs_[c];
        const float4* w4 = (const float4*)&ws[c * 32];
#pragma unroll
        for (int j4 = 0; j4 < 8; j4++) {
            float4 w = w4[j4];
            acc[j4*4+0] += zv * w.x; acc[j4*4+1] += zv * w.y;
            acc[j4*4+2] += zv * w.z; acc[j4*4+3] += zv * w.w;
        }
    }
    int n = base + tid;
    float4* yo = (float4*)&y[(size_t)n * 32];
    float4* ao = (float4*)&agg[(size_t)n * 32];
#pragma unroll
    for (int j4 = 0; j4 < 8; j4++) {
        float4 v = make_float4(acc[j4*4], acc[j4*4+1], acc[j4*4+2], acc[j4*4+3]);
        yo[j4] = v; ao[j4] = v;
    }
}

// agg[dst] += y[src] : 32 lanes per edge
__global__ __launch_bounds__(256) void k_edge(const int* __restrict__ ei,
                                              const float* __restrict__ y,
                                              float* __restrict__ agg) {
    int tid = blockIdx.x * 256 + threadIdx.x;
    int e = tid >> 5;
    if (e >= N_EDGES) return;
    int c = tid & 31;
    int s = ei[e];
    int d = ei[N_EDGES + e];
    atomicAdd(&agg[(size_t)d * 32 + c], y[(size_t)s * 32 + c]);
}

// t = relu(relu(agg+b1) @ W2 + b2); write h; accumulate BN stats (sum, sumsq)
__global__ __launch_bounds__(256) void k_mlp(const float* __restrict__ agg,
                                             const float* __restrict__ b1,
                                             const float* __restrict__ W2,
                                             const float* __restrict__ b2,
                                             float* __restrict__ h,
                                             float* __restrict__ stats) {
    __shared__ __align__(16) float ts[256 * 33];
    __shared__ __align__(16) float ws[1024];
    __shared__ float b1s[32], b2s[32];
    __shared__ float sp[8][32], sq[8][32];
    int tid = threadIdx.x, base = blockIdx.x * 256;
    for (int i = tid; i < 1024; i += 256) ws[i] = W2[i];
    if (tid < 32) { b1s[tid] = b1[tid]; b2s[tid] = b2[tid]; }
    int cnt = min(256, N_NODES - base);
    for (int i = tid; i < cnt * 32; i += 256) ts[(i >> 5) * 33 + (i & 31)] = agg[(size_t)base * 32 + i];
    __syncthreads();
    float t[32];
    if (tid < cnt) {
        float z[32];
#pragma unroll
        for (int c = 0; c < 32; c++) z[c] = fmaxf(ts[tid * 33 + c] + b1s[c], 0.f);
        float acc[32];
#pragma unroll
        for (int j = 0; j < 32; j++) acc[j] = b2s[j];
        for (int c = 0; c < 32; c++) {
            float zv = z[c];
            const float4* w4 = (const float4*)&ws[c * 32];
#pragma unroll
            for (int j4 = 0; j4 < 8; j4++) {
                float4 w = w4[j4];
                acc[j4*4+0] += zv * w.x; acc[j4*4+1] += zv * w.y;
                acc[j4*4+2] += zv * w.z; acc[j4*4+3] += zv * w.w;
            }
        }
#pragma unroll
        for (int j = 0; j < 32; j++) t[j] = fmaxf(acc[j], 0.f);
    } else {
#pragma unroll
        for (int j = 0; j < 32; j++) t[j] = 0.f;
    }
    // each thread only rewrites its own row (no cross-thread hazard)
#pragma unroll
    for (int c = 0; c < 32; c++) ts[tid * 33 + c] = t[c];
    __syncthreads();
    {
        int c = tid & 31, g = tid >> 5;
        float s = 0.f, q = 0.f;
        for (int r = g * 32; r < g * 32 + 32; r++) { float v = ts[r * 33 + c]; s += v; q += v * v; }
        sp[g][c] = s; sq[g][c] = q;
    }
    __syncthreads();
    if (tid < 32) {
        float s = 0.f, q = 0.f;
#pragma unroll
        for (int g = 0; g < 8; g++) { s += sp[g][tid]; q += sq[g][tid]; }
        atomicAdd(&stats[tid], s);
        atomicAdd(&stats[32 + tid], q);
    }
    for (int i = tid; i < cnt * 32; i += 256) h[(size_t)base * 32 + i] = ts[(i >> 5) * 33 + (i & 31)];
}

__global__ void k_bnprep(const float* __restrict__ stats,
                         const float* __restrict__ g,
                         const float* __restrict__ be,
                         float* __restrict__ aff) {
    int j = threadIdx.x;
    if (j >= 32) return;
    float inv_n = 1.f / (float)N_NODES;
    float mean = stats[j] * inv_n;
    float var = stats[32 + j] * inv_n - mean * mean;
    float a = g[j] * rsqrtf(var + BN_EPS);
    aff[j] = a;
    aff[32 + j] = be[j] - mean * a;
}

__device__ __forceinline__ int lbound(const int* __restrict__ b, int val) {
    int lo = 0, hi = N_NODES;
    while (lo < hi) { int mid = (lo + hi) >> 1; if (b[mid] < val) lo = mid + 1; else hi = mid; }
    return lo;
}

// pooled[g] = sum over nodes of graph g of (h*a + c)  (batch is sorted)
__global__ __launch_bounds__(256) void k_pool(const float* __restrict__ h,
                                              const int* __restrict__ batch,
                                              const float* __restrict__ aff,
                                              float* __restrict__ pooled) {
    __shared__ float sp[8][32];
    int g = blockIdx.x;
    int start = lbound(batch, g), end = lbound(batch, g + 1);
    int c = threadIdx.x & 31, gg = threadIdx.x >> 5;
    float acc = 0.f;
    for (int r = start + gg; r < end; r += 8) acc += h[(size_t)r * 32 + c];
    sp[gg][c] = acc;
    __syncthreads();
    if (threadIdx.x < 32) {
        float s = 0.f;
#pragma unroll
        for (int k = 0; k < 8; k++) s += sp[k][threadIdx.x];
        float a = aff[threadIdx.x], cc = aff[32 + threadIdx.x];
        pooled[g * 32 + threadIdx.x] = a * s + cc * (float)(end - start);
    }
}

// xd = relu(pooled @ W + b) -> xc[:, 0:128]  (ldc=256)
__global__ __launch_bounds__(256) void k_xd(const float* __restrict__ pooled,
                                            const float* __restrict__ W,
                                            const float* __restrict__ b,
                                            float* __restrict__ xc) {
    int t = blockIdx.x * 256 + threadIdx.x;
    int row = t >> 7, col = t & 127;
    if (row >= BATCH) return;
    float acc = b[col];
    for (int k = 0; k < 32; k++) acc += pooled[row * 32 + k] * W[k * 128 + col];
    xc[row * 256 + col] = fmaxf(acc, 0.f);
}

// ---------------- protein branch ----------------

// Wt[i][o*8+k] = convW[o][i][k]
__global__ __launch_bounds__(256) void k_trw(const float* __restrict__ convW,
                                             float* __restrict__ Wt) {
    int t = blockIdx.x * 256 + threadIdx.x;
    if (t >= 32 * SEQ * 8) return;
    int o = t / (SEQ * 8), r = t % (SEQ * 8), i = r >> 3, k = r & 7;
    Wt[i * 256 + o * 8 + k] = convW[t];
}

// per-b: S[v][o*8+k] = sum_{i: t[b,i]=v} W[o,i,k]; conv[b,o,l] = sum_{v,k} S*emb[v,l+k]
__global__ __launch_bounds__(256) void k_prot(const int* __restrict__ target,
                                              const float* __restrict__ Wt,
                                              const float* __restrict__ emb,
                                              const float* __restrict__ convb,
                                              float* __restrict__ conv) {
    __shared__ __align__(16) float S[VOC * 256];
    __shared__ __align__(16) float embs[VOC * EMBD];
    __shared__ int tv[SEQ];
    int tid = threadIdx.x, b = blockIdx.x;
    for (int i = tid; i < VOC * 256; i += 256) S[i] = 0.f;
    for (int i = tid; i < VOC * EMBD; i += 256) embs[i] = emb[i];
    for (int i = tid; i < SEQ; i += 256) tv[i] = target[(size_t)b * SEQ + i];
    __syncthreads();
#pragma unroll 4
    for (int i = 0; i < SEQ; i++) {
        int v = tv[i];
        S[v * 256 + tid] += Wt[i * 256 + tid];
    }
    __syncthreads();
    for (int j = tid; j < 32 * 121; j += 256) {
        int o = j / 121, l = j % 121;
        float acc = convb[o];
        const float* so = &S[o * 8];
        for (int v = 0; v < VOC; v++) {
            const float* e = &embs[v * EMBD + l];
            const float* sv = &so[v * 256];
#pragma unroll
            for (int k = 0; k < 8; k++) acc += sv[k] * e[k];
        }
        conv[(size_t)b * 3872 + j] = acc;
    }
}

// ---------------- head GEMMs ----------------

__global__ __launch_bounds__(256) void k_init_bias(float* __restrict__ C, int ldc, int coff,
                                                   const float* __restrict__ bias, int nb) {
    int t = blockIdx.x * 256 + threadIdx.x;
    int row = t / nb, col = t % nb;
    if (row >= BATCH) return;
    C[row * ldc + coff + col] = bias[col];
}

// C(tile 64x128) = A[M x K] @ W[K x N]; M=1024. grid = mtc*ntc*ksplits.
template <bool ATOMIC, bool RELU>
__global__ __launch_bounds__(256) void k_gemm(const float* __restrict__ A, int lda,
                                              const float* __restrict__ W, int ldw,
                                              const float* __restrict__ bias,
                                              float* __restrict__ C, int ldc, int coff,
                                              int mtc, int ntc, int klen) {
    __shared__ __align__(16) float As[128 * 68];
    int bid = blockIdx.x;
    int mt = bid % mtc, nt = (bid / mtc) % ntc, ks = bid / (mtc * ntc);
    int row0 = mt * 64, col0 = nt * 128, k0 = ks * klen;
    int tid = threadIdx.x;
    int j = tid & 127, rh = tid >> 7;
    float acc[32];
#pragma unroll
    for (int m = 0; m < 32; m++) acc[m] = (ATOMIC || bias == nullptr) ? 0.f : bias[col0 + j];
    int lr = tid >> 2, l4 = tid & 3;
    for (int kc = 0; kc < klen; kc += 128) {
        int cc = min(128, klen - kc);
        __syncthreads();
        for (int kk = l4; kk < cc; kk += 4)
            As[kk * 68 + lr] = A[(size_t)(row0 + lr) * lda + k0 + kc + kk];
        __syncthreads();
        const float* wrow = &W[(size_t)(k0 + kc) * ldw + col0 + j];
        for (int kk = 0; kk < cc; kk++) {
            float w = wrow[(size_t)kk * ldw];
            const float4* a4 = (const float4*)&As[kk * 68 + rh * 32];
#pragma unroll
            for (int m4 = 0; m4 < 8; m4++) {
                float4 a = a4[m4];
                acc[m4*4+0] += a.x * w; acc[m4*4+1] += a.y * w;
                acc[m4*4+2] += a.z * w; acc[m4*4+3] += a.w * w;
            }
        }
    }
#pragma unroll
    for (int m = 0; m < 32; m++) {
        int row = row0 + rh * 32 + m;
        float* p = &C[(size_t)row * ldc + coff + col0 + j];
        if (ATOMIC) atomicAdd(p, acc[m]);
        else { float v = acc[m]; if (RELU) v = fmaxf(v, 0.f); *p = v; }
    }
}

// out[row] = relu(xc2[row]) . out_W + out_b  (one 64-lane wave per row)
__global__ __launch_bounds__(256) void k_out(const float* __restrict__ xc2,
                                             const float* __restrict__ W,
                                             const float* __restrict__ b,
                                             float* __restrict__ out) {
    int gt = blockIdx.x * 256 + threadIdx.x;
    int wid = gt >> 6, lane = gt & 63;
    if (wid >= BATCH) return;
    float4 xv = ((const float4*)&xc2[(size_t)wid * 256])[lane];
    float4 wv = ((const float4*)W)[lane];
    float s = fmaxf(xv.x, 0.f) * wv.x + fmaxf(xv.y, 0.f) * wv.y +
              fmaxf(xv.z, 0.f) * wv.z + fmaxf(xv.w, 0.f) * wv.w;
    for (int off = 32; off; off >>= 1) s += __shfl_down(s, off, 64);
    if (lane == 0) out[wid] = s + b[0];
}

// ---------------- launch ----------------

extern "C" void kernel_launch(void* const* d_in, const int* in_sizes, int n_in,
                              void* d_out, int out_size, void* d_ws, size_t ws_size,
                              hipStream_t stream) {
    const float* x      = (const float*)d_in[0];
    const int*   ei     = (const int*)d_in[1];
    const int*   batch  = (const int*)d_in[2];
    const int*   target = (const int*)d_in[3];
    const float* W1a = (const float*)d_in[4];
    const float* b1a = (const float*)d_in[5];
    const float* W2a = (const float*)d_in[6];
    const float* b2a = (const float*)d_in[7];
    const float* g1  = (const float*)d_in[8];
    const float* be1 = (const float*)d_in[9];
    const float* Ws1 = (const float*)d_in[10];
    const float* bs1 = (const float*)d_in[11];
    const float* Ws2 = (const float*)d_in[12];
    const float* bs2 = (const float*)d_in[13];
    const float* gs  = (const float*)d_in[14];
    const float* bes = (const float*)d_in[15];
    const float* fc1xd_W = (const float*)d_in[16];
    const float* fc1xd_b = (const float*)d_in[17];
    const float* emb   = (const float*)d_in[18];
    const float* convW = (const float*)d_in[19];
    const float* convb = (const float*)d_in[20];
    const float* fcxt_W = (const float*)d_in[21];
    const float* fcxt_b = (const float*)d_in[22];
    const float* fc1_W = (const float*)d_in[23];
    const float* fc1_b = (const float*)d_in[24];
    const float* fc2_W = (const float*)d_in[25];
    const float* fc2_b = (const float*)d_in[26];
    const float* out_W = (const float*)d_in[27];
    const float* out_b = (const float*)d_in[28];
    float* out = (float*)d_out;

    char* ws = (char*)d_ws;
    const size_t NB32 = (size_t)N_NODES * 32 * 4;   // 25.6 MB
    float* y    = (float*)(ws);
    float* agg  = (float*)(ws + NB32);
    float* h    = (float*)(ws + 2 * NB32);
    float* stats = (float*)(ws + 3 * NB32);            // 5*64 floats
    float* aff   = (float*)(ws + 3 * NB32 + 1536);     // 5*64 floats
    float* pooled = (float*)(ws + 3 * NB32 + 3072);    // 1024*32
    float* xc  = (float*)(ws + 3 * NB32 + 3072 + 131072);            // 1024*256
    float* xc1 = (float*)(ws + 3 * NB32 + 3072 + 131072 + 1048576);  // 1024*1024
    float* xc2 = (float*)(ws + 3 * NB32 + 3072 + 131072 + 1048576 + 4194304); // 1024*256
    float* Wt   = agg;  // reused after graph phase (1 MB)
    float* conv = y;    // reused after graph phase (15.9 MB)

    hipMemsetAsync(stats, 0, 5 * 64 * 4, stream);

    const int PROJ78_G = (N_NODES + 127) / 128;
    const int NODE_G   = (N_NODES + 255) / 256;
    const int EDGE_G   = (N_EDGES * 32) / 256;

    // layer 1
    k_proj78<<<PROJ78_G, 128, 0, stream>>>(x, W1a, y, agg);
    k_edge<<<EDGE_G, 256, 0, stream>>>(ei, y, agg);
    k_mlp<<<NODE_G, 256, 0, stream>>>(agg, b1a, W2a, b2a, h, stats);
    k_bnprep<<<1, 64, 0, stream>>>(stats, g1, be1, aff);
    // layers 2-5
    for (int i = 0; i < 4; i++) {
        k_proj32<<<NODE_G, 256, 0, stream>>>(h, aff + i * 64, Ws1 + i * 1024, y, agg);
        k_edge<<<EDGE_G, 256, 0, stream>>>(ei, y, agg);
        k_mlp<<<NODE_G, 256, 0, stream>>>(agg, bs1 + i * 32, Ws2 + i * 1024, bs2 + i * 32,
                                          h, stats + (i + 1) * 64);
        k_bnprep<<<1, 64, 0, stream>>>(stats + (i + 1) * 64, gs + i * 32, bes + i * 32,
                                       aff + (i + 1) * 64);
    }
    // pooling + drug head  -> xc[:, :128]
    k_pool<<<BATCH, 256, 0, stream>>>(h, batch, aff + 4 * 64, pooled);
    k_xd<<<(BATCH * 128) / 256, 256, 0, stream>>>(pooled, fc1xd_W, fc1xd_b, xc);
    // protein branch -> xc[:, 128:256]
    k_trw<<<(32 * SEQ * 8) / 256, 256, 0, stream>>>(convW, Wt);
    k_prot<<<BATCH, 256, 0, stream>>>(target, Wt, emb, convb, conv);
    k_init_bias<<<(BATCH * 128) / 256, 256, 0, stream>>>(xc, 256, 128, fcxt_b, 128);
    k_gemm<true, false><<<16 * 1 * 8, 256, 0, stream>>>(conv, 3872, fcxt_W, 128, nullptr,
                                                        xc, 256, 128, 16, 1, 484);
    // joint head
    k_gemm<false, true><<<16 * 8 * 1, 256, 0, stream>>>(xc, 256, fc1_W, 1024, fc1_b,
                                                        xc1, 1024, 0, 16, 8, 256);
    k_init_bias<<<(BATCH * 256) / 256, 256, 0, stream>>>(xc2, 256, 0, fc2_b, 256);
    k_gemm<true, false><<<16 * 2 * 8, 256, 0, stream>>>(xc1, 1024, fc2_W, 256, nullptr,
                                                        xc2, 256, 0, 16, 2, 128);
    k_out<<<(BATCH * 64) / 256, 256, 0, stream>>>(xc2, out_W, out_b, out);
}